// Round 11
// baseline (182.788 us; speedup 1.0000x reference)
//
#include <hip/hip_runtime.h>
#include <hip/hip_bf16.h>

// GAT layer for MI355X (gfx950). FP32 in/out.
// R10 post-mortem: flash4's adj stream (128B-per-row nibbles, 32KB pitch,
// ~65K concurrent row-streams) runs at 1.88 TB/s = DRAM page thrash; in-flight
// bytes were ample, so concurrency was never the limiter. flash5 bulk-stages
// adj per 128-k sub-chunk with 512B-contiguous-per-row runs (8 back-to-back
// int4 per thread), bitpacks to a 2KB LDS mask (double-buffered), and consumes
// masks+LDS-B in the MFMA steps. One raw lgkm-barrier per sub; next sub's
// loads issued pre-barrier, consumed a full compute-phase later. LDS-staged
// fp32 epilogue kills flash4's 2.4x write amplification (78->33 MB).
// Pipeline: wsplit -> wh(+f12) -> flash5 -> reduce.

typedef __bf16 bf16;
typedef __attribute__((ext_vector_type(8))) __bf16 bf16x8;
typedef __attribute__((ext_vector_type(4))) float f32x4;

#define NN 8192
#define F_IN 256
#define F_OUT 128
#define LOG2E 1.44269504088896f
#define ALPHA 0.2f
#define KSLICES 8

// ---------------------------------------------------------------------------
// K0: split W into hi/lo bf16 planes once.
// ---------------------------------------------------------------------------
__global__ __launch_bounds__(256) void gat_wsplit(const float* __restrict__ W,
                                                  bf16* __restrict__ Whi,
                                                  bf16* __restrict__ Wlo) {
    const int i = blockIdx.x * 256 + threadIdx.x;
    const float v = W[i];
    const bf16 h = (bf16)v;
    Whi[i] = h;
    Wlo[i] = (bf16)(v - (float)h);
}

__device__ __forceinline__ void split8(const float* __restrict__ p,
                                       bf16x8& hi, bf16x8& lo) {
    const float4 u = *(const float4*)p;
    const float4 v = *(const float4*)(p + 4);
    float f[8] = {u.x, u.y, u.z, u.w, v.x, v.y, v.z, v.w};
#pragma unroll
    for (int j = 0; j < 8; ++j) {
        const bf16 h = (bf16)f[j];
        hi[j] = h;
        lo[j] = (bf16)(f[j] - (float)h);
    }
}

// ---------------------------------------------------------------------------
// K1: Wh = h @ W^T (split-bf16, fp32 acc) -> WhT bf16 [128][8192]; f1/f2
// computed in-block from the fp32 acc (16-lane shuffle reduce), pre-scaled.
// ---------------------------------------------------------------------------
__global__ __launch_bounds__(128) void gat_wh(const float* __restrict__ h,
                                              const bf16* __restrict__ Whi,
                                              const bf16* __restrict__ Wlo,
                                              const float* __restrict__ a,
                                              bf16* __restrict__ WhT,
                                              float* __restrict__ f1L,
                                              float* __restrict__ f2L) {
    const int tid = threadIdx.x;
    const int wv = tid >> 6;
    const int l15 = tid & 15;
    const int g = (tid & 63) >> 4;
    const int rowbase = blockIdx.x * 32 + wv * 16;

    f32x4 acc[8];
    const f32x4 zz = {0.f, 0.f, 0.f, 0.f};
#pragma unroll
    for (int nf = 0; nf < 8; ++nf) acc[nf] = zz;

#pragma unroll
    for (int ks = 0; ks < 8; ++ks) {
        const int k = ks * 32 + g * 8;
        bf16x8 ah, al;
        split8(h + (size_t)(rowbase + l15) * F_IN + k, ah, al);
#pragma unroll
        for (int nf = 0; nf < 8; ++nf) {
            const bf16x8 bh = *(const bf16x8*)(Whi + (size_t)(nf * 16 + l15) * F_IN + k);
            const bf16x8 bl = *(const bf16x8*)(Wlo + (size_t)(nf * 16 + l15) * F_IN + k);
            acc[nf] = __builtin_amdgcn_mfma_f32_16x16x32_bf16(ah, bh, acc[nf], 0, 0, 0);
            acc[nf] = __builtin_amdgcn_mfma_f32_16x16x32_bf16(ah, bl, acc[nf], 0, 0, 0);
            acc[nf] = __builtin_amdgcn_mfma_f32_16x16x32_bf16(al, bh, acc[nf], 0, 0, 0);
        }
    }

#pragma unroll
    for (int nf = 0; nf < 8; ++nf)
#pragma unroll
        for (int r = 0; r < 4; ++r)
            WhT[(size_t)(nf * 16 + l15) * NN + rowbase + g * 4 + r] = (bf16)acc[nf][r];

    float a1c[8], a2c[8];
#pragma unroll
    for (int nf = 0; nf < 8; ++nf) {
        a1c[nf] = a[nf * 16 + l15];
        a2c[nf] = a[F_OUT + nf * 16 + l15];
    }
#pragma unroll
    for (int r = 0; r < 4; ++r) {
        float s1 = 0.f, s2 = 0.f;
#pragma unroll
        for (int nf = 0; nf < 8; ++nf) {
            s1 += acc[nf][r] * a1c[nf];
            s2 += acc[nf][r] * a2c[nf];
        }
        s1 += __shfl_xor(s1, 1, 16);
        s1 += __shfl_xor(s1, 2, 16);
        s1 += __shfl_xor(s1, 4, 16);
        s1 += __shfl_xor(s1, 8, 16);
        s2 += __shfl_xor(s2, 1, 16);
        s2 += __shfl_xor(s2, 2, 16);
        s2 += __shfl_xor(s2, 4, 16);
        s2 += __shfl_xor(s2, 8, 16);
        if (l15 == 0) {
            f1L[rowbase + g * 4 + r] = s1 * LOG2E;
            f2L[rowbase + g * 4 + r] = s2 * LOG2E;
        }
    }
}

// ---------------------------------------------------------------------------
// K2: flash5. Grid 512 = 64 row-tiles(128 rows) x 8 k-slices(1024 k);
// blockIdx&7 = ks aligns each 256 KB B-slice to one XCD's L2.
// 512 thr, 8 waves; wave = 16 rows x 128 F_OUT-cols. 8 sub-chunks of 128 k.
// Per sub: [pack prev-loaded adj regs -> 2KB LDS mask; write B regs -> 32KB
// LDS] [issue next sub's loads: 8x int4 adj (128B contiguous/thread) +
// 4x bf16x8 B] [lgkmcnt(0); s_barrier] [4 MFMA steps from LDS].
// LDS 72 KB -> 2 blocks/CU; cross-block overlap hides staging.
// ---------------------------------------------------------------------------
#define LOADS(IT)                                                                \
    do {                                                                         \
        const int k0_ = (IT) * 128;                                              \
        A0 = *(const int4*)(arp + k0_);                                          \
        A1 = *(const int4*)(arp + k0_ + 4);                                      \
        A2 = *(const int4*)(arp + k0_ + 8);                                      \
        A3 = *(const int4*)(arp + k0_ + 12);                                     \
        A4 = *(const int4*)(arp + k0_ + 16);                                     \
        A5 = *(const int4*)(arp + k0_ + 20);                                     \
        A6 = *(const int4*)(arp + k0_ + 24);                                     \
        A7 = *(const int4*)(arp + k0_ + 28);                                     \
        B0 = *(const bf16x8*)(bsrc0 + k0_);                                      \
        B1 = *(const bf16x8*)(bsrc1 + k0_);                                      \
        B2 = *(const bf16x8*)(bsrc2 + k0_);                                      \
        B3 = *(const bf16x8*)(bsrc3 + k0_);                                      \
    } while (0)

#define BIT(V, SH) ((V) > 0 ? (1u << (SH)) : 0u)

__global__ __launch_bounds__(512, 4) void gat_flash5(
        const int* __restrict__ adj,
        const bf16* __restrict__ WhT,
        const float* __restrict__ f1L,
        const float* __restrict__ f2L,
        float* __restrict__ O_part,
        float* __restrict__ rs_part) {
    __shared__ __align__(16) char lds[73728];
    // [0,65536): B dbuf (2x32KB)  [65536,69632): mask dbuf (2x2KB)
    // [69632,73728): f2 slice     epilogue reuse: accL[128][132] f32

    const int tid = threadIdx.x;
    const int wv = tid >> 6;
    const int l = tid & 63;
    const int l15 = l & 15;
    const int g = l >> 4;
    const int rb = blockIdx.x >> 3;
    const int ks = blockIdx.x & 7;
    const int row0 = rb * 128;
    const int lrow = wv * 16 + l15;  // compute-side local row
    const int srow = tid >> 2;       // staging-side local row
    const int scol = tid & 3;        // staging col quarter (32 ints)

    const float f1a = f1L[row0 + lrow];
    const int* arp = adj + (size_t)(row0 + srow) * NN + ks * 1024 + scol * 32;

    // B staging sources: unit u = j*512 + tid -> col cc = u>>4, 16B-unit ku = u&15
    const bf16* bsrc0 = WhT + (size_t)((0 * 512 + tid) >> 4) * NN + ks * 1024 + ((0 * 512 + tid) & 15) * 8;
    const bf16* bsrc1 = WhT + (size_t)((1 * 512 + tid) >> 4) * NN + ks * 1024 + ((1 * 512 + tid) & 15) * 8;
    const bf16* bsrc2 = WhT + (size_t)((2 * 512 + tid) >> 4) * NN + ks * 1024 + ((2 * 512 + tid) & 15) * 8;
    const bf16* bsrc3 = WhT + (size_t)((3 * 512 + tid) >> 4) * NN + ks * 1024 + ((3 * 512 + tid) & 15) * 8;
    // B LDS destinations (swizzled)
    int bdst[4];
#pragma unroll
    for (int j = 0; j < 4; ++j) {
        const int u = j * 512 + tid;
        const int cc = u >> 4;
        const int ku = u & 15;
        bdst[j] = (cc * 256 + ku * 16) ^ ((cc & 7) << 4);
    }
    const int mdst = srow * 16 + scol * 4;

    f32x4 acc[8];
    const f32x4 zz = {0.f, 0.f, 0.f, 0.f};
#pragma unroll
    for (int nf = 0; nf < 8; ++nf) acc[nf] = zz;
    float rs0 = 0.f;

    // f2 slice -> LDS (visible after first barrier)
    {
        const float2 v = *(const float2*)(f2L + ks * 1024 + tid * 2);
        *(float2*)(lds + 69632 + tid * 8) = v;
    }

    int4 A0, A1, A2, A3, A4, A5, A6, A7;
    bf16x8 B0, B1, B2, B3;
    LOADS(0);

#pragma unroll
    for (int it = 0; it < 8; ++it) {
        const int base = (it & 1) * 32768;
        const int mbase = 65536 + (it & 1) * 2048;

        // ---- pack adj regs -> mask word; write B regs -> LDS ----
        unsigned int w = BIT(A0.x, 0) | BIT(A0.y, 1) | BIT(A0.z, 2) | BIT(A0.w, 3) |
                         BIT(A1.x, 4) | BIT(A1.y, 5) | BIT(A1.z, 6) | BIT(A1.w, 7) |
                         BIT(A2.x, 8) | BIT(A2.y, 9) | BIT(A2.z, 10) | BIT(A2.w, 11) |
                         BIT(A3.x, 12) | BIT(A3.y, 13) | BIT(A3.z, 14) | BIT(A3.w, 15) |
                         BIT(A4.x, 16) | BIT(A4.y, 17) | BIT(A4.z, 18) | BIT(A4.w, 19) |
                         BIT(A5.x, 20) | BIT(A5.y, 21) | BIT(A5.z, 22) | BIT(A5.w, 23) |
                         BIT(A6.x, 24) | BIT(A6.y, 25) | BIT(A6.z, 26) | BIT(A6.w, 27) |
                         BIT(A7.x, 28) | BIT(A7.y, 29) | BIT(A7.z, 30) | BIT(A7.w, 31);
        *(unsigned int*)(lds + mbase + mdst) = w;
        *(bf16x8*)(lds + base + bdst[0]) = B0;
        *(bf16x8*)(lds + base + bdst[1]) = B1;
        *(bf16x8*)(lds + base + bdst[2]) = B2;
        *(bf16x8*)(lds + base + bdst[3]) = B3;
        __builtin_amdgcn_sched_barrier(0);

        // ---- issue next sub's loads (in flight across the barrier) ----
        if (it < 7) LOADS(it + 1);
        __builtin_amdgcn_sched_barrier(0);

        asm volatile("s_waitcnt lgkmcnt(0)" ::: "memory");
        __builtin_amdgcn_s_barrier();
        __builtin_amdgcn_sched_barrier(0);

        // ---- 4 MFMA steps from LDS ----
#pragma unroll
        for (int s = 0; s < 4; ++s) {
            const unsigned int mb =
                *(const unsigned char*)(lds + mbase + lrow * 16 + s * 4 + g);
            const float4 fa = *(const float4*)(lds + 69632 + (it * 4 + s) * 128 + g * 32);
            const float4 fb = *(const float4*)(lds + 69632 + (it * 4 + s) * 128 + g * 32 + 16);
            const float ff[8] = {fa.x, fa.y, fa.z, fa.w, fb.x, fb.y, fb.z, fb.w};

            bf16x8 pa;
#pragma unroll
            for (int j = 0; j < 8; ++j) {
                const float x = f1a + ff[j];
                const float e = __builtin_amdgcn_exp2f(fmaxf(x, ALPHA * x));
                pa[j] = (bf16)((mb & (1u << j)) ? e : 0.f);
            }
#pragma unroll
            for (int j = 0; j < 8; ++j) rs0 += (float)pa[j];

            __builtin_amdgcn_s_setprio(1);
#pragma unroll
            for (int nf = 0; nf < 8; ++nf) {
                const int c = nf * 16 + l15;
                const int off = base + ((c * 256 + s * 64 + g * 16) ^ ((c & 7) << 4));
                const bf16x8 bh = *(const bf16x8*)(lds + off);
                acc[nf] = __builtin_amdgcn_mfma_f32_16x16x32_bf16(pa, bh, acc[nf], 0, 0, 0);
            }
            __builtin_amdgcn_s_setprio(0);
        }
    }

    // rowsum partial
    rs0 += __shfl_xor(rs0, 16);
    rs0 += __shfl_xor(rs0, 32);
    if (l < 16) rs_part[(size_t)ks * NN + row0 + wv * 16 + l15] = rs0;

    // ---- LDS-staged epilogue (contiguous fp32 writes, no write amp) ----
    asm volatile("s_waitcnt lgkmcnt(0) vmcnt(0)" ::: "memory");
    __builtin_amdgcn_s_barrier();

    float* accL = (float*)lds;  // [128][132]
#pragma unroll
    for (int nf = 0; nf < 8; ++nf)
#pragma unroll
        for (int r = 0; r < 4; ++r)
            accL[(wv * 16 + g * 4 + r) * 132 + nf * 16 + l15] = acc[nf][r];

    asm volatile("s_waitcnt lgkmcnt(0)" ::: "memory");
    __builtin_amdgcn_s_barrier();

    float* ob = O_part + ((size_t)ks << 20) + (size_t)(row0 + srow) * F_OUT + scol * 32;
    const float* al = accL + srow * 132 + scol * 32;
#pragma unroll
    for (int j = 0; j < 8; ++j)
        *(float4*)(ob + j * 4) = *(const float4*)(al + j * 4);
}

// ---------------------------------------------------------------------------
// K3: reduce k-slices: out = (sum_s O_part[s]) / (sum_s rs_part[s]).
// ---------------------------------------------------------------------------
__global__ __launch_bounds__(256) void gat_reduce(const float* __restrict__ O_part,
                                                  const float* __restrict__ rs_part,
                                                  float* __restrict__ out) {
    const int idx = blockIdx.x * 256 + threadIdx.x;
    const int r = idx >> 5;
    const int c = (idx & 31) * 4;
    float rsum = 0.f;
#pragma unroll
    for (int s = 0; s < KSLICES; ++s) rsum += rs_part[(size_t)s * NN + r];
    float4 o = {0.f, 0.f, 0.f, 0.f};
#pragma unroll
    for (int s = 0; s < KSLICES; ++s) {
        const float4 v = *(const float4*)(O_part + ((size_t)s << 20) + (size_t)r * F_OUT + c);
        o.x += v.x;
        o.y += v.y;
        o.z += v.z;
        o.w += v.w;
    }
    const float inv = 1.0f / rsum;
    o.x *= inv;
    o.y *= inv;
    o.z *= inv;
    o.w *= inv;
    *(float4*)(out + (size_t)r * F_OUT + c) = o;
}

// ---------------------------------------------------------------------------
extern "C" void kernel_launch(void* const* d_in, const int* in_sizes, int n_in,
                              void* d_out, int out_size, void* d_ws, size_t ws_size,
                              hipStream_t stream) {
    const float* h = (const float*)d_in[0];  // (8192, 256) fp32
    const int* adj = (const int*)d_in[1];    // (8192, 8192) int32
    const float* W = (const float*)d_in[2];  // (128, 256) fp32
    const float* a = (const float*)d_in[3];  // (1, 256) fp32
    float* out = (float*)d_out;              // (8192, 128) fp32

    char* ws = (char*)d_ws;
    const size_t MB = 1024 * 1024;
    bf16* WhT = (bf16*)ws;                         // 2 MB
    float* f1L = (float*)(ws + 2 * MB);            // 32 KB
    float* f2L = f1L + NN;                         // 32 KB
    bf16* Whi = (bf16*)(ws + 2 * MB + 64 * 1024);  // 64 KB
    bf16* Wlo = (bf16*)(ws + 2 * MB + 128 * 1024); // 64 KB
    float* rs_part = (float*)(ws + 3 * MB);        // 256 KB
    float* O_part = (float*)(ws + 4 * MB);         // 32 MB

    gat_wsplit<<<128, 256, 0, stream>>>(W, Whi, Wlo);
    gat_wh<<<256, 128, 0, stream>>>(h, Whi, Wlo, a, WhT, f1L, f2L);
    gat_flash5<<<512, 512, 0, stream>>>(adj, WhT, f1L, f2L, O_part, rs_part);
    gat_reduce<<<NN * F_OUT / 4 / 256, 256, 0, stream>>>(O_part, rs_part, out);
}

// Round 12
// 126.211 us; speedup vs baseline: 1.4483x; 1.4483x over previous
//
#include <hip/hip_runtime.h>
#include <hip/hip_bf16.h>

// GAT layer for MI355X (gfx950). FP32 in/out.
// R11 post-mortem: every fused variant gave each lane a PRIVATE 128B run ->
// one wave instruction touches 16-64 cache lines (16B used each) -> request
// path throttles at ~1.5-1.9 TB/s regardless of schedule (the R4-R11
// invariant). Fast kernels on this chip (fills 87%, copy 6.3 TB/s) are
// lane-contiguous (1KB/instruction). So: adj is consumed by a dedicated pack
// kernel with perfect per-instruction coalescing (wave=row, lane i at +16i B),
// bitmask layout [ks][row][128B]; flash6 stages mask+f2+B through LDS (all
// coalesced), 4 blocks/CU, bulk-synchronous, contiguous epilogue.
// Pipeline: wsplit -> wh(+f12) -> pack -> flash6 -> reduce.

typedef __bf16 bf16;
typedef __attribute__((ext_vector_type(8))) __bf16 bf16x8;
typedef __attribute__((ext_vector_type(4))) float f32x4;

#define NN 8192
#define F_IN 256
#define F_OUT 128
#define LOG2E 1.44269504088896f
#define ALPHA 0.2f
#define KSLICES 8

// ---------------------------------------------------------------------------
// K0: pack adj -> bitmask, lane-contiguous reads. Wave = one row; per iter the
// wave reads 2x1KB contiguous (lane i at +16i). Lane nibble (4 cmp) + 1
// shfl_xor -> even lanes hold one mask byte (bit j = col 8b+j). Mask layout:
// maskP[ks][row][128B] so flash6's staging read is contiguous per block.
// ---------------------------------------------------------------------------
__global__ __launch_bounds__(256) void gat_pack(const int* __restrict__ adj,
                                                unsigned char* __restrict__ maskP) {
    const int row = blockIdx.x * 4 + (threadIdx.x >> 6);
    const int l = threadIdx.x & 63;
    const int* rowp = adj + (size_t)row * NN;

#pragma unroll 4
    for (int iter = 0; iter < 16; ++iter) {
        const int base = iter * 512;
        const int4 v1 = *(const int4*)(rowp + base + l * 4);
        const int4 v2 = *(const int4*)(rowp + base + 256 + l * 4);
        unsigned int n1 = (v1.x > 0 ? 1u : 0u) | (v1.y > 0 ? 2u : 0u) |
                          (v1.z > 0 ? 4u : 0u) | (v1.w > 0 ? 8u : 0u);
        unsigned int n2 = (v2.x > 0 ? 1u : 0u) | (v2.y > 0 ? 2u : 0u) |
                          (v2.z > 0 ? 4u : 0u) | (v2.w > 0 ? 8u : 0u);
        const unsigned int p1 = __shfl_xor(n1, 1);
        const unsigned int p2 = __shfl_xor(n2, 1);
        if ((l & 1) == 0) {
            const int b1 = iter * 64 + (l >> 1);        // byte index 0..1023
            const int b2 = b1 + 32;
            maskP[((size_t)(b1 >> 7) << 20) + (size_t)row * 128 + (b1 & 127)] =
                (unsigned char)(n1 | (p1 << 4));
            maskP[((size_t)(b2 >> 7) << 20) + (size_t)row * 128 + (b2 & 127)] =
                (unsigned char)(n2 | (p2 << 4));
        }
    }
}

// ---------------------------------------------------------------------------
// K0b: split W into hi/lo bf16 planes once.
// ---------------------------------------------------------------------------
__global__ __launch_bounds__(256) void gat_wsplit(const float* __restrict__ W,
                                                  bf16* __restrict__ Whi,
                                                  bf16* __restrict__ Wlo) {
    const int i = blockIdx.x * 256 + threadIdx.x;
    const float v = W[i];
    const bf16 h = (bf16)v;
    Whi[i] = h;
    Wlo[i] = (bf16)(v - (float)h);
}

__device__ __forceinline__ void split8(const float* __restrict__ p,
                                       bf16x8& hi, bf16x8& lo) {
    const float4 u = *(const float4*)p;
    const float4 v = *(const float4*)(p + 4);
    float f[8] = {u.x, u.y, u.z, u.w, v.x, v.y, v.z, v.w};
#pragma unroll
    for (int j = 0; j < 8; ++j) {
        const bf16 h = (bf16)f[j];
        hi[j] = h;
        lo[j] = (bf16)(f[j] - (float)h);
    }
}

// ---------------------------------------------------------------------------
// K1: Wh = h @ W^T (split-bf16, fp32 acc) -> WhT bf16 [128][8192]; f1/f2
// computed in-block from the fp32 acc (16-lane shuffle reduce), pre-scaled.
// ---------------------------------------------------------------------------
__global__ __launch_bounds__(128) void gat_wh(const float* __restrict__ h,
                                              const bf16* __restrict__ Whi,
                                              const bf16* __restrict__ Wlo,
                                              const float* __restrict__ a,
                                              bf16* __restrict__ WhT,
                                              float* __restrict__ f1L,
                                              float* __restrict__ f2L) {
    const int tid = threadIdx.x;
    const int wv = tid >> 6;
    const int l15 = tid & 15;
    const int g = (tid & 63) >> 4;
    const int rowbase = blockIdx.x * 32 + wv * 16;

    f32x4 acc[8];
    const f32x4 zz = {0.f, 0.f, 0.f, 0.f};
#pragma unroll
    for (int nf = 0; nf < 8; ++nf) acc[nf] = zz;

#pragma unroll
    for (int ks = 0; ks < 8; ++ks) {
        const int k = ks * 32 + g * 8;
        bf16x8 ah, al;
        split8(h + (size_t)(rowbase + l15) * F_IN + k, ah, al);
#pragma unroll
        for (int nf = 0; nf < 8; ++nf) {
            const bf16x8 bh = *(const bf16x8*)(Whi + (size_t)(nf * 16 + l15) * F_IN + k);
            const bf16x8 bl = *(const bf16x8*)(Wlo + (size_t)(nf * 16 + l15) * F_IN + k);
            acc[nf] = __builtin_amdgcn_mfma_f32_16x16x32_bf16(ah, bh, acc[nf], 0, 0, 0);
            acc[nf] = __builtin_amdgcn_mfma_f32_16x16x32_bf16(ah, bl, acc[nf], 0, 0, 0);
            acc[nf] = __builtin_amdgcn_mfma_f32_16x16x32_bf16(al, bh, acc[nf], 0, 0, 0);
        }
    }

#pragma unroll
    for (int nf = 0; nf < 8; ++nf)
#pragma unroll
        for (int r = 0; r < 4; ++r)
            WhT[(size_t)(nf * 16 + l15) * NN + rowbase + g * 4 + r] = (bf16)acc[nf][r];

    float a1c[8], a2c[8];
#pragma unroll
    for (int nf = 0; nf < 8; ++nf) {
        a1c[nf] = a[nf * 16 + l15];
        a2c[nf] = a[F_OUT + nf * 16 + l15];
    }
#pragma unroll
    for (int r = 0; r < 4; ++r) {
        float s1 = 0.f, s2 = 0.f;
#pragma unroll
        for (int nf = 0; nf < 8; ++nf) {
            s1 += acc[nf][r] * a1c[nf];
            s2 += acc[nf][r] * a2c[nf];
        }
        s1 += __shfl_xor(s1, 1, 16);
        s1 += __shfl_xor(s1, 2, 16);
        s1 += __shfl_xor(s1, 4, 16);
        s1 += __shfl_xor(s1, 8, 16);
        s2 += __shfl_xor(s2, 1, 16);
        s2 += __shfl_xor(s2, 2, 16);
        s2 += __shfl_xor(s2, 4, 16);
        s2 += __shfl_xor(s2, 8, 16);
        if (l15 == 0) {
            f1L[rowbase + g * 4 + r] = s1 * LOG2E;
            f2L[rowbase + g * 4 + r] = s2 * LOG2E;
        }
    }
}

// ---------------------------------------------------------------------------
// K2: flash6. Grid 512 = 64 row-tiles(128 rows) x 8 k-slices(1024 k).
// 512 thr, 8 waves; wave = 16 rows x 128 cols. 8 chunks of k=128:
//   [sync][stage B 32KB (lane-contiguous, swizzled LDS) + mask 2KB][sync]
//   [4 steps: mask byte + f2 from LDS -> 8 exp -> pa; 8 ds_read_b128 + 8 MFMA]
// 39.4 KB LDS -> 4 blocks/CU (cross-block overlap hides staging).
// Epilogue: accL halves -> contiguous fp32 row writes (no write amp).
// ---------------------------------------------------------------------------
__global__ __launch_bounds__(512, 4) void gat_flash6(
        const unsigned char* __restrict__ maskP,
        const bf16* __restrict__ WhT,
        const float* __restrict__ f1L,
        const float* __restrict__ f2L,
        float* __restrict__ O_part,
        float* __restrict__ rs_part) {
    __shared__ __align__(16) char lds[39424];
    // [0,32768): B chunk [128c][128k] swizzled
    // [32768,35328): mask chunk [128 rows][20B padded stride, 16B used]
    // [35328,39424): f2 slice (1024 f32)
    // epilogue reuse: accL[64][132] f32 at offset 0

    const int tid = threadIdx.x;
    const int wv = tid >> 6;
    const int l = tid & 63;
    const int l15 = l & 15;
    const int g = l >> 4;
    const int rb = blockIdx.x >> 3;
    const int ks = blockIdx.x & 7;
    const int row0 = rb * 128;
    const int lrow = wv * 16 + l15;

    const float f1a = f1L[row0 + lrow];

    const int mr = tid >> 2;   // mask staging row
    const int mseg = tid & 3;  // 4B segment
    const unsigned char* msrc =
        maskP + ((size_t)ks << 20) + (size_t)(row0 + mr) * 128 + mseg * 4;

    f32x4 acc[8];
    const f32x4 zz = {0.f, 0.f, 0.f, 0.f};
#pragma unroll
    for (int nf = 0; nf < 8; ++nf) acc[nf] = zz;
    float rs0 = 0.f;

    // f2 slice -> LDS (visible after the first stage barrier pair)
    {
        const float2 v = *(const float2*)(f2L + ks * 1024 + tid * 2);
        *(float2*)(lds + 35328 + tid * 8) = v;
    }

    for (int it = 0; it < 8; ++it) {
        __syncthreads();  // previous chunk fully consumed
        // ---- stage mask chunk (2KB) ----
        const unsigned int mw = *(const unsigned int*)(msrc + it * 16);
        *(unsigned int*)(lds + 32768 + mr * 20 + mseg * 4) = mw;
        // ---- stage B chunk (32KB), lane-contiguous reads, swizzled writes ----
#pragma unroll
        for (int j = 0; j < 4; ++j) {
            const int u = j * 512 + tid;
            const int cc = u >> 4;
            const int ku = u & 15;
            const bf16x8 v =
                *(const bf16x8*)(WhT + (size_t)cc * NN + ks * 1024 + it * 128 + ku * 8);
            *(bf16x8*)(lds + ((cc * 256 + ku * 16) ^ ((cc & 7) << 4))) = v;
        }
        __syncthreads();  // staged data visible

        // ---- 4 MFMA steps (k=32 each) ----
#pragma unroll
        for (int s = 0; s < 4; ++s) {
            const unsigned int mb =
                *(const unsigned char*)(lds + 32768 + lrow * 20 + s * 4 + g);
            const int t = it * 4 + s;
            const float4 fa = *(const float4*)(lds + 35328 + t * 128 + g * 32);
            const float4 fb = *(const float4*)(lds + 35328 + t * 128 + g * 32 + 16);
            const float ff[8] = {fa.x, fa.y, fa.z, fa.w, fb.x, fb.y, fb.z, fb.w};

            bf16x8 pa;
#pragma unroll
            for (int j = 0; j < 8; ++j) {
                const float x = f1a + ff[j];
                const float e = __builtin_amdgcn_exp2f(fmaxf(x, ALPHA * x));
                pa[j] = (bf16)((mb & (1u << j)) ? e : 0.f);
            }
#pragma unroll
            for (int j = 0; j < 8; ++j) rs0 += (float)pa[j];

            __builtin_amdgcn_s_setprio(1);
#pragma unroll
            for (int nf = 0; nf < 8; ++nf) {
                const int c = nf * 16 + l15;
                const bf16x8 bh = *(const bf16x8*)(
                    lds + ((c * 256 + s * 64 + g * 16) ^ ((c & 7) << 4)));
                acc[nf] = __builtin_amdgcn_mfma_f32_16x16x32_bf16(pa, bh, acc[nf], 0, 0, 0);
            }
            __builtin_amdgcn_s_setprio(0);
        }
    }

    // rowsum partial (combine the 4 g-groups)
    rs0 += __shfl_xor(rs0, 16);
    rs0 += __shfl_xor(rs0, 32);
    if (l < 16) rs_part[(size_t)ks * NN + row0 + lrow] = rs0;

    // ---- epilogue: two halves through accL[64][132], contiguous writes ----
    float* accL = (float*)lds;
#pragma unroll
    for (int half = 0; half < 2; ++half) {
        __syncthreads();
        if ((wv >> 2) == half) {
            const int rbase = (wv & 3) * 16;
#pragma unroll
            for (int nf = 0; nf < 8; ++nf)
#pragma unroll
                for (int r = 0; r < 4; ++r)
                    accL[(rbase + g * 4 + r) * 132 + nf * 16 + l15] = acc[nf][r];
        }
        __syncthreads();
        const int rr = tid >> 3;  // 0..63
        const int seg = tid & 7;  // 16 floats each
        float* dst = O_part + ((size_t)ks << 20) +
                     (size_t)(row0 + half * 64 + rr) * F_OUT + seg * 16;
        const float* src = accL + rr * 132 + seg * 16;
        *(float4*)(dst + 0) = *(const float4*)(src + 0);
        *(float4*)(dst + 4) = *(const float4*)(src + 4);
        *(float4*)(dst + 8) = *(const float4*)(src + 8);
        *(float4*)(dst + 12) = *(const float4*)(src + 12);
    }
}

// ---------------------------------------------------------------------------
// K3: reduce k-slices: out = (sum_s O_part[s]) / (sum_s rs_part[s]).
// ---------------------------------------------------------------------------
__global__ __launch_bounds__(256) void gat_reduce(const float* __restrict__ O_part,
                                                  const float* __restrict__ rs_part,
                                                  float* __restrict__ out) {
    const int idx = blockIdx.x * 256 + threadIdx.x;
    const int r = idx >> 5;
    const int c = (idx & 31) * 4;
    float rsum = 0.f;
#pragma unroll
    for (int s = 0; s < KSLICES; ++s) rsum += rs_part[(size_t)s * NN + r];
    float4 o = {0.f, 0.f, 0.f, 0.f};
#pragma unroll
    for (int s = 0; s < KSLICES; ++s) {
        const float4 v =
            *(const float4*)(O_part + ((size_t)s << 20) + (size_t)r * F_OUT + c);
        o.x += v.x;
        o.y += v.y;
        o.z += v.z;
        o.w += v.w;
    }
    const float inv = 1.0f / rsum;
    o.x *= inv;
    o.y *= inv;
    o.z *= inv;
    o.w *= inv;
    *(float4*)(out + (size_t)r * F_OUT + c) = o;
}

// ---------------------------------------------------------------------------
extern "C" void kernel_launch(void* const* d_in, const int* in_sizes, int n_in,
                              void* d_out, int out_size, void* d_ws, size_t ws_size,
                              hipStream_t stream) {
    const float* h = (const float*)d_in[0];  // (8192, 256) fp32
    const int* adj = (const int*)d_in[1];    // (8192, 8192) int32
    const float* W = (const float*)d_in[2];  // (128, 256) fp32
    const float* a = (const float*)d_in[3];  // (1, 256) fp32
    float* out = (float*)d_out;              // (8192, 128) fp32

    char* ws = (char*)d_ws;
    const size_t MB = 1024 * 1024;
    bf16* WhT = (bf16*)ws;                          // 2 MB
    float* f1L = (float*)(ws + 2 * MB);             // 32 KB
    float* f2L = f1L + NN;                          // 32 KB
    bf16* Whi = (bf16*)(ws + 2 * MB + 64 * 1024);   // 64 KB
    bf16* Wlo = (bf16*)(ws + 2 * MB + 128 * 1024);  // 64 KB
    unsigned char* maskP = (unsigned char*)(ws + 3 * MB);  // 8 MB [ks][row][128B]
    float* rs_part = (float*)(ws + 11 * MB);        // 256 KB
    float* O_part = (float*)(ws + 12 * MB);         // 32 MB

    gat_wsplit<<<128, 256, 0, stream>>>(W, Whi, Wlo);
    gat_wh<<<256, 128, 0, stream>>>(h, Whi, Wlo, a, WhT, f1L, f2L);
    gat_pack<<<2048, 256, 0, stream>>>(adj, maskP);
    gat_flash6<<<512, 512, 0, stream>>>(maskP, WhT, f1L, f2L, O_part, rs_part);
    gat_reduce<<<NN * F_OUT / 4 / 256, 256, 0, stream>>>(O_part, rs_part, out);
}

// Round 13
// 123.438 us; speedup vs baseline: 1.4808x; 1.0225x over previous
//
#include <hip/hip_runtime.h>
#include <hip/hip_bf16.h>

// GAT layer for MI355X (gfx950). FP32 in/out.
// R12 post-mortem: split pack+flash works (126 us) but serializes the 256 MB
// adj stream against the MFMA compute and round-trips an 8 MB mask. flash7
// fuses pack INTO flash keeping the winning access shape: >=512B contiguous
// per instruction (2 rows x 512B per int4 wave-load; each row consumed in
// 2KB contiguous pieces), register bit-pack (4 cmp + 1 shfl), LDS mask.
// Fill-kernel evidence says per-instruction contiguity is what matters, not
// long runs (fills jump grid-stride between instructions at 87% peak).
// Pipeline (3 dispatches): wh(inline W split, +f12) -> flash7 -> reduce.

typedef __bf16 bf16;
typedef __attribute__((ext_vector_type(8))) __bf16 bf16x8;
typedef __attribute__((ext_vector_type(4))) float f32x4;

#define NN 8192
#define F_IN 256
#define F_OUT 128
#define LOG2E 1.44269504088896f
#define ALPHA 0.2f
#define KSLICES 8

__device__ __forceinline__ void split8(const float* __restrict__ p,
                                       bf16x8& hi, bf16x8& lo) {
    const float4 u = *(const float4*)p;
    const float4 v = *(const float4*)(p + 4);
    float f[8] = {u.x, u.y, u.z, u.w, v.x, v.y, v.z, v.w};
#pragma unroll
    for (int j = 0; j < 8; ++j) {
        const bf16 h = (bf16)f[j];
        hi[j] = h;
        lo[j] = (bf16)(f[j] - (float)h);
    }
}

// ---------------------------------------------------------------------------
// K1: Wh = h @ W^T (split-bf16 both operands, fp32 acc) -> WhT bf16 [128][8192];
// f1/f2 computed in-block from the fp32 acc (16-lane shuffle reduce).
// 256 blocks x 128 thr.
// ---------------------------------------------------------------------------
__global__ __launch_bounds__(128) void gat_wh(const float* __restrict__ h,
                                              const float* __restrict__ W,
                                              const float* __restrict__ a,
                                              bf16* __restrict__ WhT,
                                              float* __restrict__ f1L,
                                              float* __restrict__ f2L) {
    const int tid = threadIdx.x;
    const int wv = tid >> 6;
    const int l15 = tid & 15;
    const int g = (tid & 63) >> 4;
    const int rowbase = blockIdx.x * 32 + wv * 16;

    f32x4 acc[8];
    const f32x4 zz = {0.f, 0.f, 0.f, 0.f};
#pragma unroll
    for (int nf = 0; nf < 8; ++nf) acc[nf] = zz;

#pragma unroll
    for (int ks = 0; ks < 8; ++ks) {
        const int k = ks * 32 + g * 8;
        bf16x8 ah, al;
        split8(h + (size_t)(rowbase + l15) * F_IN + k, ah, al);
#pragma unroll
        for (int nf = 0; nf < 8; ++nf) {
            bf16x8 bh, bl;
            split8(W + (size_t)(nf * 16 + l15) * F_IN + k, bh, bl);
            acc[nf] = __builtin_amdgcn_mfma_f32_16x16x32_bf16(ah, bh, acc[nf], 0, 0, 0);
            acc[nf] = __builtin_amdgcn_mfma_f32_16x16x32_bf16(ah, bl, acc[nf], 0, 0, 0);
            acc[nf] = __builtin_amdgcn_mfma_f32_16x16x32_bf16(al, bh, acc[nf], 0, 0, 0);
        }
    }

#pragma unroll
    for (int nf = 0; nf < 8; ++nf)
#pragma unroll
        for (int r = 0; r < 4; ++r)
            WhT[(size_t)(nf * 16 + l15) * NN + rowbase + g * 4 + r] = (bf16)acc[nf][r];

    float a1c[8], a2c[8];
#pragma unroll
    for (int nf = 0; nf < 8; ++nf) {
        a1c[nf] = a[nf * 16 + l15];
        a2c[nf] = a[F_OUT + nf * 16 + l15];
    }
#pragma unroll
    for (int r = 0; r < 4; ++r) {
        float s1 = 0.f, s2 = 0.f;
#pragma unroll
        for (int nf = 0; nf < 8; ++nf) {
            s1 += acc[nf][r] * a1c[nf];
            s2 += acc[nf][r] * a2c[nf];
        }
        s1 += __shfl_xor(s1, 1, 16);
        s1 += __shfl_xor(s1, 2, 16);
        s1 += __shfl_xor(s1, 4, 16);
        s1 += __shfl_xor(s1, 8, 16);
        s2 += __shfl_xor(s2, 1, 16);
        s2 += __shfl_xor(s2, 2, 16);
        s2 += __shfl_xor(s2, 4, 16);
        s2 += __shfl_xor(s2, 8, 16);
        if (l15 == 0) {
            f1L[rowbase + g * 4 + r] = s1 * LOG2E;
            f2L[rowbase + g * 4 + r] = s2 * LOG2E;
        }
    }
}

// ---------------------------------------------------------------------------
// K2: flash7 — fused adj-pack + masked softmax + PV.
// Grid 512 = 64 row-tiles(128 rows) x 8 k-slices(1024 k). 512 thr, 8 waves;
// wave = 16 rows x 128 F_OUT-cols. 2 super-chunks of k=512:
//   [sync][stage mask: wave packs ITS 16 rows; per inst 2 rows x 512B
//    contiguous int4; 4 cmp + shfl_xor -> even lanes write mask byte to LDS]
//   then 4 B-chunks of k=128: [sync][stage B 32KB lane-contiguous, swizzled]
//   [sync][4 MFMA steps: mask byte + f2 (LDS) -> 8 exp -> pa; 8 ds_read+MFMA].
// LDS 45.6 KB -> 2-3 blocks/CU; cross-block overlap hides staging.
// Epilogue: accL halves -> contiguous fp32 writes. Partials over ks.
// ---------------------------------------------------------------------------
__global__ __launch_bounds__(512, 4) void gat_flash7(
        const int* __restrict__ adj,
        const bf16* __restrict__ WhT,
        const float* __restrict__ f1L,
        const float* __restrict__ f2L,
        float* __restrict__ O_part,
        float* __restrict__ rs_part) {
    __shared__ __align__(16) char lds[45568];
    // [0,32768): B chunk [128c][128k] swizzled
    // [32768,41472): mask [128 rows][68B padded, 64 used]  (one super = 512 bits)
    // [41472,45568): f2 slice (1024 f32)
    // epilogue reuse: accL[64][132] f32 at offset 0
#define MOFF 32768
#define FOFF 41472

    const int tid = threadIdx.x;
    const int wv = tid >> 6;
    const int l = tid & 63;
    const int l15 = l & 15;
    const int g = l >> 4;
    const int half = l >> 5;     // staging: which row of the pair
    const int lane32 = l & 31;   // staging: 16B column unit
    const int rb = blockIdx.x >> 3;
    const int ks = blockIdx.x & 7;
    const int row0 = rb * 128;
    const int lrow = wv * 16 + l15;

    const float f1a = f1L[row0 + lrow];

    f32x4 acc[8];
    const f32x4 zz = {0.f, 0.f, 0.f, 0.f};
#pragma unroll
    for (int nf = 0; nf < 8; ++nf) acc[nf] = zz;
    float rs0 = 0.f;

    // f2 slice -> LDS (visible after the first barrier)
    {
        const float2 v = *(const float2*)(f2L + ks * 1024 + tid * 2);
        *(float2*)(lds + FOFF + tid * 8) = v;
    }

    for (int su = 0; su < 2; ++su) {
        __syncthreads();  // prev super's mask fully consumed
        // ---- stage mask: wave packs its own 16 rows, 2KB contiguous/row ----
#pragma unroll
        for (int i = 0; i < 8; ++i) {
            const int lr = wv * 16 + 2 * i + half;
            const int* ap = adj + (size_t)(row0 + lr) * NN + ks * 1024 + su * 512 + lane32 * 4;
#pragma unroll
            for (int p = 0; p < 4; ++p) {
                const int4 v = *(const int4*)(ap + p * 128);
                const unsigned int n = (v.x > 0 ? 1u : 0u) | (v.y > 0 ? 2u : 0u) |
                                       (v.z > 0 ? 4u : 0u) | (v.w > 0 ? 8u : 0u);
                const unsigned int o = __shfl_xor(n, 1);
                if ((l & 1) == 0)
                    *(unsigned char*)(lds + MOFF + lr * 68 + p * 16 + (lane32 >> 1)) =
                        (unsigned char)(n | (o << 4));
            }
        }

#pragma unroll
        for (int bc = 0; bc < 4; ++bc) {
            __syncthreads();  // prev B chunk consumed (also orders mask writes)
            // ---- stage B chunk [128c][128k], lane-contiguous, swizzled ----
            const int kg = ks * 1024 + su * 512 + bc * 128;
#pragma unroll
            for (int j = 0; j < 4; ++j) {
                const int u = j * 512 + tid;
                const int cc = u >> 4;
                const int ku = u & 15;
                const bf16x8 v = *(const bf16x8*)(WhT + (size_t)cc * NN + kg + ku * 8);
                *(bf16x8*)(lds + ((cc * 256 + ku * 16) ^ ((cc & 7) << 4))) = v;
            }
            __syncthreads();  // staged data visible

            // ---- 4 MFMA steps (k=32 each) ----
#pragma unroll
            for (int s = 0; s < 4; ++s) {
                const int t = bc * 4 + s;         // step within super (0..15)
                const int tt = su * 16 + t;       // step within slice (0..31)
                const unsigned int mb =
                    *(const unsigned char*)(lds + MOFF + lrow * 68 + t * 4 + g);
                const float4 fa = *(const float4*)(lds + FOFF + tt * 128 + g * 32);
                const float4 fb = *(const float4*)(lds + FOFF + tt * 128 + g * 32 + 16);
                const float ff[8] = {fa.x, fa.y, fa.z, fa.w, fb.x, fb.y, fb.z, fb.w};

                bf16x8 pa;
#pragma unroll
                for (int j = 0; j < 8; ++j) {
                    const float x = f1a + ff[j];
                    const float e = __builtin_amdgcn_exp2f(fmaxf(x, ALPHA * x));
                    pa[j] = (bf16)((mb & (1u << j)) ? e : 0.f);
                }
#pragma unroll
                for (int j = 0; j < 8; ++j) rs0 += (float)pa[j];

                __builtin_amdgcn_s_setprio(1);
#pragma unroll
                for (int nf = 0; nf < 8; ++nf) {
                    const int c = nf * 16 + l15;
                    const bf16x8 bh = *(const bf16x8*)(
                        lds + ((c * 256 + s * 64 + g * 16) ^ ((c & 7) << 4)));
                    acc[nf] =
                        __builtin_amdgcn_mfma_f32_16x16x32_bf16(pa, bh, acc[nf], 0, 0, 0);
                }
                __builtin_amdgcn_s_setprio(0);
            }
        }
    }

    // rowsum partial (combine the 4 g-groups)
    rs0 += __shfl_xor(rs0, 16);
    rs0 += __shfl_xor(rs0, 32);
    if (l < 16) rs_part[(size_t)ks * NN + row0 + lrow] = rs0;

    // ---- epilogue: two halves through accL[64][132], contiguous writes ----
    float* accL = (float*)lds;
#pragma unroll
    for (int hh = 0; hh < 2; ++hh) {
        __syncthreads();
        if ((wv >> 2) == hh) {
            const int rbase = (wv & 3) * 16;
#pragma unroll
            for (int nf = 0; nf < 8; ++nf)
#pragma unroll
                for (int r = 0; r < 4; ++r)
                    accL[(rbase + g * 4 + r) * 132 + nf * 16 + l15] = acc[nf][r];
        }
        __syncthreads();
        const int rr = tid >> 3;
        const int seg = tid & 7;
        float* dst = O_part + ((size_t)ks << 20) +
                     (size_t)(row0 + hh * 64 + rr) * F_OUT + seg * 16;
        const float* src = accL + rr * 132 + seg * 16;
        *(float4*)(dst + 0) = *(const float4*)(src + 0);
        *(float4*)(dst + 4) = *(const float4*)(src + 4);
        *(float4*)(dst + 8) = *(const float4*)(src + 8);
        *(float4*)(dst + 12) = *(const float4*)(src + 12);
    }
#undef MOFF
#undef FOFF
}

// ---------------------------------------------------------------------------
// K3: reduce k-slices: out = (sum_s O_part[s]) / (sum_s rs_part[s]).
// ---------------------------------------------------------------------------
__global__ __launch_bounds__(256) void gat_reduce(const float* __restrict__ O_part,
                                                  const float* __restrict__ rs_part,
                                                  float* __restrict__ out) {
    const int idx = blockIdx.x * 256 + threadIdx.x;
    const int r = idx >> 5;
    const int c = (idx & 31) * 4;
    float rsum = 0.f;
#pragma unroll
    for (int s = 0; s < KSLICES; ++s) rsum += rs_part[(size_t)s * NN + r];
    float4 o = {0.f, 0.f, 0.f, 0.f};
#pragma unroll
    for (int s = 0; s < KSLICES; ++s) {
        const float4 v =
            *(const float4*)(O_part + ((size_t)s << 20) + (size_t)r * F_OUT + c);
        o.x += v.x;
        o.y += v.y;
        o.z += v.z;
        o.w += v.w;
    }
    const float inv = 1.0f / rsum;
    o.x *= inv;
    o.y *= inv;
    o.z *= inv;
    o.w *= inv;
    *(float4*)(out + (size_t)r * F_OUT + c) = o;
}

// ---------------------------------------------------------------------------
extern "C" void kernel_launch(void* const* d_in, const int* in_sizes, int n_in,
                              void* d_out, int out_size, void* d_ws, size_t ws_size,
                              hipStream_t stream) {
    const float* h = (const float*)d_in[0];  // (8192, 256) fp32
    const int* adj = (const int*)d_in[1];    // (8192, 8192) int32
    const float* W = (const float*)d_in[2];  // (128, 256) fp32
    const float* a = (const float*)d_in[3];  // (1, 256) fp32
    float* out = (float*)d_out;              // (8192, 128) fp32

    char* ws = (char*)d_ws;
    const size_t MB = 1024 * 1024;
    bf16* WhT = (bf16*)ws;                   // 2 MB
    float* f1L = (float*)(ws + 2 * MB);      // 32 KB
    float* f2L = f1L + NN;                   // 32 KB
    float* rs_part = (float*)(ws + 3 * MB);  // 256 KB
    float* O_part = (float*)(ws + 4 * MB);   // 32 MB

    gat_wh<<<256, 128, 0, stream>>>(h, W, a, WhT, f1L, f2L);
    gat_flash7<<<512, 512, 0, stream>>>(adj, WhT, f1L, f2L, O_part, rs_part);
    gat_reduce<<<NN * F_OUT / 4 / 256, 256, 0, stream>>>(O_part, rs_part, out);
}